// Round 2
// baseline (623.138 us; speedup 1.0000x reference)
//
#include <hip/hip_runtime.h>

#define N_NODES 100000
#define N_EDGES 1600000
#define FEAT 64

// ---------------- CSR build ----------------

__global__ void count_deg_kernel(const int* __restrict__ dst, int* __restrict__ deg,
                                 int n_edges) {
    int i = blockIdx.x * blockDim.x + threadIdx.x;
    int stride = gridDim.x * blockDim.x;
    for (; i < n_edges; i += stride) {
        atomicAdd(&deg[dst[i]], 1);
    }
}

// per-block sums of deg (256 elems per block)
__global__ void scan_block_sums(const int* __restrict__ deg, int* __restrict__ bsum, int n) {
    __shared__ int sdata[256];
    int t = threadIdx.x;
    int i = blockIdx.x * 256 + t;
    sdata[t] = (i < n) ? deg[i] : 0;
    __syncthreads();
    for (int s = 128; s > 0; s >>= 1) {
        if (t < s) sdata[t] += sdata[t + s];
        __syncthreads();
    }
    if (t == 0) bsum[blockIdx.x] = sdata[0];
}

// exclusive scan of block sums (single block, nb <= 512)
__global__ void scan_partials(const int* __restrict__ bsum, int* __restrict__ bpref, int nb) {
    __shared__ int sdata[512];
    int t = threadIdx.x;
    int v = (t < nb) ? bsum[t] : 0;
    sdata[t] = v;
    __syncthreads();
    for (int off = 1; off < 512; off <<= 1) {
        int add = (t >= off) ? sdata[t - off] : 0;
        __syncthreads();
        sdata[t] += add;
        __syncthreads();
    }
    if (t < nb) bpref[t] = sdata[t] - v;  // exclusive prefix
}

// per-block exclusive scan + add block prefix -> row_start, cursor
__global__ void scan_final(const int* __restrict__ deg, const int* __restrict__ bpref,
                           int* __restrict__ row_start, int* __restrict__ cursor, int n) {
    __shared__ int sdata[256];
    int t = threadIdx.x;
    int i = blockIdx.x * 256 + t;
    int v = (i < n) ? deg[i] : 0;
    sdata[t] = v;
    __syncthreads();
    for (int off = 1; off < 256; off <<= 1) {
        int add = (t >= off) ? sdata[t - off] : 0;
        __syncthreads();
        sdata[t] += add;
        __syncthreads();
    }
    int incl = sdata[t];
    int excl = incl - v;
    int base = bpref[blockIdx.x];
    if (i < n) {
        row_start[i] = base + excl;
        cursor[i]    = base + excl;
        if (i == n - 1) row_start[n] = base + incl;  // total = N_EDGES
    }
}

__global__ void reorder_kernel(const int* __restrict__ src, const int* __restrict__ dst,
                               int* __restrict__ cursor, int* __restrict__ src_sorted,
                               int n_edges) {
    int i = blockIdx.x * blockDim.x + threadIdx.x;
    int stride = gridDim.x * blockDim.x;
    for (; i < n_edges; i += stride) {
        int slot = atomicAdd(&cursor[dst[i]], 1);
        src_sorted[slot] = src[i];
    }
}

// ---------------- fused GIN layer ----------------
// One wave per node. lane = feature. Aggregate incoming src rows via CSR
// (no atomics), add self, then 64x64 matmul via readlane broadcast with the
// W row held per-lane in 64 VGPRs. Optional ReLU. OUTF=64 for hidden layers,
// OUTF=10 for the classifier head.
template <int OUTF, bool RELU>
__global__ __launch_bounds__(256) void gin_layer(
    const float* __restrict__ in, const int* __restrict__ row_start,
    const int* __restrict__ src_sorted, const float* __restrict__ W,
    const float* __restrict__ bias, float* __restrict__ out, int n_nodes) {
    const int lane = threadIdx.x & 63;
    int wid = (int)((blockIdx.x * blockDim.x + threadIdx.x) >> 6);
    const int nw = (int)((gridDim.x * blockDim.x) >> 6);
    wid = __builtin_amdgcn_readfirstlane(wid);  // wave-uniform -> SGPR

    // lane j computes output feature j: needs W[j][k] for k=0..63
    const int jc = (OUTF == 64) ? lane : ((lane < OUTF) ? lane : 0);
    float Wc[64];
#pragma unroll
    for (int k = 0; k < 64; ++k) Wc[k] = W[jc * 64 + k];
    const float bj = bias[jc];

    for (int node = wid; node < n_nodes; node += nw) {
        const int e0 = row_start[node];
        const int e1 = row_start[node + 1];
        float r = in[(size_t)node * FEAT + lane];
        int e = e0;
        for (; e + 4 <= e1; e += 4) {
            int s0 = src_sorted[e + 0];
            int s1 = src_sorted[e + 1];
            int s2 = src_sorted[e + 2];
            int s3 = src_sorted[e + 3];
            float v0 = in[(size_t)s0 * FEAT + lane];
            float v1 = in[(size_t)s1 * FEAT + lane];
            float v2 = in[(size_t)s2 * FEAT + lane];
            float v3 = in[(size_t)s3 * FEAT + lane];
            r += v0 + v1 + v2 + v3;
        }
        for (; e < e1; ++e) {
            r += in[(size_t)src_sorted[e] * FEAT + lane];
        }

        // out[j] = b[j] + sum_k row[k] * W[j][k]
        float acc = bj;
#pragma unroll
        for (int k = 0; k < 64; ++k) {
            float rv = __int_as_float(__builtin_amdgcn_readlane(__float_as_int(r), k));
            acc = fmaf(rv, Wc[k], acc);
        }
        if (OUTF == 64 || lane < OUTF) {
            out[(size_t)node * OUTF + lane] = RELU ? fmaxf(acc, 0.0f) : acc;
        }
    }
}

// ---------------- launcher ----------------

extern "C" void kernel_launch(void* const* d_in, const int* in_sizes, int n_in,
                              void* d_out, int out_size, void* d_ws, size_t ws_size,
                              hipStream_t stream) {
    const float* x  = (const float*)d_in[0];
    const int*   ei = (const int*)d_in[1];
    const int*   src = ei;
    const int*   dst = ei + N_EDGES;
    const float* W1 = (const float*)d_in[2];
    const float* b1 = (const float*)d_in[3];
    const float* W2 = (const float*)d_in[4];
    const float* b2 = (const float*)d_in[5];
    const float* W3 = (const float*)d_in[6];
    const float* b3 = (const float*)d_in[7];
    const float* W4 = (const float*)d_in[8];
    const float* b4 = (const float*)d_in[9];
    float* out = (float*)d_out;

    // workspace layout (256B aligned)
    char* ws = (char*)d_ws;
    size_t off = 0;
    auto carve = [&](size_t bytes) {
        char* p = ws + off;
        off += (bytes + 255) & ~(size_t)255;
        return p;
    };
    int* deg        = (int*)carve(N_NODES * sizeof(int));
    int* cursor     = (int*)carve(N_NODES * sizeof(int));
    int* row_start  = (int*)carve((N_NODES + 1) * sizeof(int));
    int* bsum       = (int*)carve(512 * sizeof(int));
    int* bpref      = (int*)carve(512 * sizeof(int));
    int* src_sorted = (int*)carve((size_t)N_EDGES * sizeof(int));
    float* h1       = (float*)carve((size_t)N_NODES * FEAT * sizeof(float));
    float* h2       = (float*)carve((size_t)N_NODES * FEAT * sizeof(float));
    (void)ws_size;

    const int NB = (N_NODES + 255) / 256;  // 391

    hipMemsetAsync(deg, 0, N_NODES * sizeof(int), stream);
    count_deg_kernel<<<2048, 256, 0, stream>>>(dst, deg, N_EDGES);
    scan_block_sums<<<NB, 256, 0, stream>>>(deg, bsum, N_NODES);
    scan_partials<<<1, 512, 0, stream>>>(bsum, bpref, NB);
    scan_final<<<NB, 256, 0, stream>>>(deg, bpref, row_start, cursor, N_NODES);
    reorder_kernel<<<2048, 256, 0, stream>>>(src, dst, cursor, src_sorted, N_EDGES);

    gin_layer<64, true><<<2048, 256, 0, stream>>>(x,  row_start, src_sorted, W1, b1, h1, N_NODES);
    gin_layer<64, true><<<2048, 256, 0, stream>>>(h1, row_start, src_sorted, W2, b2, h2, N_NODES);
    gin_layer<64, true><<<2048, 256, 0, stream>>>(h2, row_start, src_sorted, W3, b3, h1, N_NODES);
    gin_layer<10, false><<<2048, 256, 0, stream>>>(h1, row_start, src_sorted, W4, b4, out, N_NODES);
}